// Round 14
// baseline (1782.897 us; speedup 1.0000x reference)
//
#include <hip/hip_runtime.h>
#include <hip/hip_bf16.h>

typedef unsigned short u16;
typedef short short8 __attribute__((ext_vector_type(8)));
typedef u16 u16x8 __attribute__((ext_vector_type(8)));
typedef float f32x4 __attribute__((ext_vector_type(4)));
typedef unsigned u32x4v __attribute__((ext_vector_type(4)));
typedef unsigned u32x2v __attribute__((ext_vector_type(2)));

#define H 1024
#define NB 16
#define SEQ 256
#define NL 4
#define VOCAB 32000
#define G4 4096
#define YSZ ((size_t)SEQ * NB * H)
#define SENT 0xFFFFFFFFu

__device__ __forceinline__ u16 f2bf(float f) {
  __hip_bfloat16 h = __float2bfloat16(f);
  return *reinterpret_cast<u16*>(&h);
}
__device__ __forceinline__ float sigm(float x) { return 1.0f / (1.0f + __expf(-x)); }
__device__ __forceinline__ float tanhfast(float x) { return 2.0f / (1.0f + __expf(-2.0f * x)) - 1.0f; }

__device__ __forceinline__ f32x4 mfma16(short8 a, short8 b, f32x4 c) {
  return __builtin_amdgcn_mfma_f32_16x16x32_bf16(a, b, c, 0, 0, 0);
}

// Device-coherent 16B load: bypass L1/L2, served by the MALL.
template <int BOFF>
__device__ __forceinline__ short8 ldg_sc(const u16* p) {
  short8 r;
  asm volatile("global_load_dwordx4 %0, %1, off offset:%2 sc0 sc1"
               : "=&v"(r) : "v"(p), "n"(BOFF));
  return r;
}
// Cached 16B load via asm (deterministic vmcnt accounting).
template <int BOFF>
__device__ __forceinline__ short8 ldg_ca(const u16* p) {
  short8 r;
  asm volatile("global_load_dwordx4 %0, %1, off offset:%2"
               : "=&v"(r) : "v"(p), "n"(BOFF));
  return r;
}

#define LD8SC(d, p)                                            \
  do {                                                         \
    d[0] = ldg_sc<0 * 64>(p); d[1] = ldg_sc<1 * 64>(p);        \
    d[2] = ldg_sc<2 * 64>(p); d[3] = ldg_sc<3 * 64>(p);        \
    d[4] = ldg_sc<4 * 64>(p); d[5] = ldg_sc<5 * 64>(p);        \
    d[6] = ldg_sc<6 * 64>(p); d[7] = ldg_sc<7 * 64>(p);        \
  } while (0)
#define LD8CA(d, p)                                            \
  do {                                                         \
    d[0] = ldg_ca<0 * 64>(p); d[1] = ldg_ca<1 * 64>(p);        \
    d[2] = ldg_ca<2 * 64>(p); d[3] = ldg_ca<3 * 64>(p);        \
    d[4] = ldg_ca<4 * 64>(p); d[5] = ldg_ca<5 * 64>(p);        \
    d[6] = ldg_ca<6 * 64>(p); d[7] = ldg_ca<7 * 64>(p);        \
  } while (0)

// 8-bit mask: bit i set iff packet i contains any sentinel dword (unwritten /
// torn). A packet is trusted only when ALL 4 dwords are non-sentinel.
__device__ __forceinline__ unsigned badmask(const short8 (&f)[8]) {
  unsigned m = 0u;
  #pragma unroll
  for (int i = 0; i < 8; ++i) {
    u32x4v d = __builtin_bit_cast(u32x4v, f[i]);
    const bool bad = (d[0] == SENT) || (d[1] == SENT) || (d[2] == SENT) || (d[3] == SENT);
    m |= bad ? (1u << i) : 0u;
  }
  return m;
}
// selective reload of one packet (exec-masked when mask bit clear)
#define REL1(miss, d, p, I) \
  if ((miss) & (1u << (I))) d[I] = ldg_sc<(I) * 64>(p)

// ---------------- small prep kernels ----------------

__global__ void cvt_bf16(const float* __restrict__ in, u16* __restrict__ out, int n8) {
  const int i = blockIdx.x * blockDim.x + threadIdx.x;
  if (i >= n8) return;
  const float4 a = ((const float4*)in)[2 * i];
  const float4 b = ((const float4*)in)[2 * i + 1];
  u16x8 o;
  o[0] = f2bf(a.x); o[1] = f2bf(a.y); o[2] = f2bf(a.z); o[3] = f2bf(a.w);
  o[4] = f2bf(b.x); o[5] = f2bf(b.y); o[6] = f2bf(b.z); o[7] = f2bf(b.w);
  *(u16x8*)(out + (size_t)i * 8) = o;
}

__global__ void bias_sum(const float* __restrict__ a, const float* __restrict__ b,
                         float* __restrict__ o, int n) {
  const int i = blockIdx.x * blockDim.x + threadIdx.x;
  if (i < n) o[i] = a[i] + b[i];
}

// sentinel refill of the polled Y buffers (every launch: replay safety).
__global__ void fill_sent(u32x4v* __restrict__ p) {
  const int i = blockIdx.x * blockDim.x + threadIdx.x;
  u32x4v v = {SENT, SENT, SENT, SENT};
  p[i] = v;
}

__global__ void gather_emb(const int* __restrict__ x, const float* __restrict__ emb,
                           u16* __restrict__ Y) {
  const int row = blockIdx.x;
  const int tok = x[row];
  const float4 v = ((const float4*)(emb + (size_t)tok * H))[threadIdx.x];
  ushort4 o;
  o.x = f2bf(v.x); o.y = f2bf(v.y); o.z = f2bf(v.z); o.w = f2bf(v.w);
  *(ushort4*)(Y + (size_t)row * H + threadIdx.x * 4) = o;
}

// ---------------- LSTM: 4-layer wavefront, K-split waves, sentinel-stamped ----------------
// 256 WGs x 256 thr (1 WG/CU). blockIdx = l*64 + jgrp; WG owns 16 j-columns.
// Wave w owns k-steps [8w, 8w+8) of all 64 slice rows (4 row-tiles).
// Whh: LDS fragment-ordered. Wih: register-resident WI[32] (asm-pinned).
// Sync: sentinel-stamped data (round-13 proven). New this round:
//  (a) selective per-packet reload poll — cuts MALL poll traffic ~4-8x
//      (full-set reload was ~16 TB/s of sc reads, congesting the MALL);
//  (b) per-wave shfl-pack publish — each wave packs its 4 j-columns with 4
//      __shfl and 16 lanes fire dwordx2 sc stores right after gates; no smh
//      LDS hop, no wave0 bottleneck; trailing barrier (lred WAR guard) sits
//      AFTER the stores, off the publish path.

__global__ __launch_bounds__(256, 1) void lstm_scan(
    const u16* __restrict__ ybase_r, u16* __restrict__ ybase_w,
    const u16* __restrict__ Wih_all, const u16* __restrict__ Whh_all,
    const float* __restrict__ bias_all, const u16* __restrict__ h0_all,
    const float* __restrict__ c0_all, float* __restrict__ hfin_all,
    float* __restrict__ cfin_all)
{
  extern __shared__ u16 sm[];  // bytes [0,131072): Whh frags; [131072,147456): lred
  u16* __restrict__ smw = sm;
  f32x4* __restrict__ lred = (f32x4*)(sm + 65536);  // u16 index 65536 = byte 131072

  const int tid = threadIdx.x;
  const int lane = tid & 63;
  const int wid = tid >> 6;
  const int l = blockIdx.x >> 6;
  const int jgrp = blockIdx.x & 63;
  const int jbase = jgrp * 16;
  const int b = lane & 15;
  const int lg = lane >> 4;
  const int m = lane & 15;
  const int j = jbase + wid * 4 + lg;

  const u16* __restrict__ Yin  = ybase_r + (size_t)l * YSZ;
  u16* __restrict__ Yout       = ybase_w + (size_t)(l + 1) * YSZ;
  const u16* __restrict__ Wih  = Wih_all + (size_t)l * G4 * H;
  const u16* __restrict__ Whh  = Whh_all + (size_t)l * G4 * H;
  const float* __restrict__ bias = bias_all + (size_t)l * G4;
  const u16* __restrict__ h0b  = h0_all + (size_t)l * NB * H;
  const float* __restrict__ c0 = c0_all + (size_t)l * NB * H;
  float* __restrict__ hfin     = hfin_all + (size_t)l * NB * H;
  float* __restrict__ cfin     = cfin_all + (size_t)l * NB * H;

  // ---- stage Whh slice into LDS, fragment-ordered (conflict-free) ----
  // (rt, ks, lane) at u16 offset rt*16384 + ks*512 + lane*8, ks = wid*8+i.
  #pragma unroll
  for (int rt = 0; rt < 4; ++rt) {
    const size_t ar = (size_t)((m & 3) * H + jbase + rt * 4 + (m >> 2));
    const u16* src = Whh + ar * H + lg * 8;
    #pragma unroll
    for (int i = 0; i < 8; ++i) {
      const int ks = wid * 8 + i;
      short8 w = *(const short8*)(src + ks * 32);
      *(short8*)(smw + (size_t)rt * 16384 + (size_t)ks * 512 + lane * 8) = w;
    }
  }
  // ---- Wih k-quarter -> registers (asm-pinned; round-11 proved streaming
  // it from cache costs 1.4 GB FETCH and 2.1x once waits are honest) ----
  short8 WI[32];
  #pragma unroll
  for (int rt = 0; rt < 4; ++rt) {
    const size_t ar = (size_t)((m & 3) * H + jbase + rt * 4 + (m >> 2));
    const u16* src = Wih + ar * H + lg * 8;
    #pragma unroll
    for (int i = 0; i < 8; ++i) {
      WI[rt * 8 + i] = *(const short8*)(src + (wid * 8 + i) * 32);
      asm volatile("" : "+v"(WI[rt * 8 + i]));
    }
  }
  __syncthreads();

  f32x4 bias4;
  bias4[0] = bias[0 * H + j];
  bias4[1] = bias[1 * H + j];
  bias4[2] = bias[2 * H + j];
  bias4[3] = bias[3 * H + j];

  float c = c0[b * H + j];
  const int boff = b * H + lg * 8;           // per-lane column base within a [16,1024] tile
  const int kboff = wid * 256;               // wave's k-quarter offset (8 ks * 32 u16)
  const u16* __restrict__ smwv = smw + (size_t)wid * 4096 + lane * 8;  // + rt*16384 + i*512

  for (int t = 0; t < SEQ; ++t) {
    const u16* xw = Yin + (size_t)t * (NB * H) + boff + kboff;
    const u16* hw = (t == 0 ? h0b : Yout + (size_t)(t - 1) * (NB * H)) + boff + kboff;

    short8 fx[8], fh[8];
    const bool needx = (l > 0);
    const bool needh = (t > 0);
    if (needx) { LD8SC(fx, xw); } else { LD8CA(fx, xw); }
    if (needh) { LD8SC(fh, hw); } else { LD8CA(fh, hw); }
    asm volatile("s_waitcnt vmcnt(0)" ::: "memory");

    if (needx || needh) {
      unsigned missx = needx ? badmask(fx) : 0u;
      unsigned missh = needh ? badmask(fh) : 0u;
      while (__any((missx | missh) != 0u)) {
        REL1(missx, fx, xw, 0); REL1(missx, fx, xw, 1);
        REL1(missx, fx, xw, 2); REL1(missx, fx, xw, 3);
        REL1(missx, fx, xw, 4); REL1(missx, fx, xw, 5);
        REL1(missx, fx, xw, 6); REL1(missx, fx, xw, 7);
        REL1(missh, fh, hw, 0); REL1(missh, fh, hw, 1);
        REL1(missh, fh, hw, 2); REL1(missh, fh, hw, 3);
        REL1(missh, fh, hw, 4); REL1(missh, fh, hw, 5);
        REL1(missh, fh, hw, 6); REL1(missh, fh, hw, 7);
        asm volatile("s_waitcnt vmcnt(0)" ::: "memory");
        if (needx) missx = badmask(fx);
        if (needh) missh = badmask(fh);
      }
    }
    __builtin_amdgcn_sched_barrier(0);

    f32x4 a0 = {0.f, 0.f, 0.f, 0.f};
    f32x4 a1 = {0.f, 0.f, 0.f, 0.f};
    f32x4 a2 = {0.f, 0.f, 0.f, 0.f};
    f32x4 a3 = {0.f, 0.f, 0.f, 0.f};

    // Zx = Wih @ x_t (register A-frags)
    #pragma unroll
    for (int i = 0; i < 8; ++i) {
      a0 = mfma16(WI[0 * 8 + i], fx[i], a0);
      a1 = mfma16(WI[1 * 8 + i], fx[i], a1);
      a2 = mfma16(WI[2 * 8 + i], fx[i], a2);
      a3 = mfma16(WI[3 * 8 + i], fx[i], a3);
    }
    // += Whh @ h_{t-1} (A-frags from LDS)
    #pragma unroll
    for (int i = 0; i < 8; ++i) {
      short8 w0 = *(const short8*)(smwv + 0 * 16384 + i * 512);
      short8 w1 = *(const short8*)(smwv + 1 * 16384 + i * 512);
      short8 w2 = *(const short8*)(smwv + 2 * 16384 + i * 512);
      short8 w3 = *(const short8*)(smwv + 3 * 16384 + i * 512);
      a0 = mfma16(w0, fh[i], a0);
      a1 = mfma16(w1, fh[i], a1);
      a2 = mfma16(w2, fh[i], a2);
      a3 = mfma16(w3, fh[i], a3);
    }

    // ---- cross-wave reduce: wave w keeps row-tile w, ships the rest via LDS ----
    if (wid != 0) lred[(0 * 4 + wid) * 64 + lane] = a0;
    if (wid != 1) lred[(1 * 4 + wid) * 64 + lane] = a1;
    if (wid != 2) lred[(2 * 4 + wid) * 64 + lane] = a2;
    if (wid != 3) lred[(3 * 4 + wid) * 64 + lane] = a3;
    __syncthreads();

    f32x4 z4 = bias4;
    if (wid == 0)      z4 += a0;
    else if (wid == 1) z4 += a1;
    else if (wid == 2) z4 += a2;
    else               z4 += a3;
    #pragma unroll
    for (int w2 = 0; w2 < 4; ++w2)
      if (w2 != wid) z4 += lred[(wid * 4 + w2) * 64 + lane];

    const float ig = sigm(z4[0]);
    const float fg = sigm(z4[1]);
    const float gg = tanhfast(z4[2]);
    const float og = sigm(z4[3]);
    c = fg * c + ig * gg;
    const float h = og * tanhfast(c);

    // ---- per-wave shfl-pack publish: 4 j-columns x 16 rows, dwordx2/row ----
    // lane (b, lg) holds h(b, j = jbase + wid*4 + lg); lane b (<16) gathers
    // lg=0..3 via shfl and stores 8B at (b, jbase + wid*4).
    const unsigned hu = (unsigned)f2bf(h);
    const unsigned p0 = (unsigned)__shfl((int)hu, b);
    const unsigned p1 = (unsigned)__shfl((int)hu, b + 16);
    const unsigned p2 = (unsigned)__shfl((int)hu, b + 32);
    const unsigned p3 = (unsigned)__shfl((int)hu, b + 48);
    if (lane < 16) {
      u32x2v pv;
      pv[0] = p0 | (p1 << 16);
      pv[1] = p2 | (p3 << 16);
      const u16* dst = Yout + (size_t)t * (NB * H) + (size_t)b * H + jbase + wid * 4;
      asm volatile("global_store_dwordx2 %0, %1, off sc0 sc1"
                   :: "v"(dst), "v"(pv) : "memory");
    }
    if (t == SEQ - 1) {
      hfin[b * H + j] = h;
      cfin[b * H + j] = c;
    }
    __syncthreads();  // lred WAR guard — after stores, off the publish path
  }
}

// ---------------- bf16 GEMM: 128x128, XCD m-clustered, 2-phase dbuf staging ----------------
// Stage next K-tile (global_load_lds) BEFORE the MFMA block; one vmcnt(0) +
// barrier per tile. Staging flies under MFMA; barrier count halves.

#define STAGE_GEMM(BUF, K0)                                                      \
  do {                                                                           \
    _Pragma("unroll")                                                            \
    for (int cc = 0; cc < 4; ++cc) {                                             \
      const int row_ = wid * 32 + cc * 8 + lr;                                   \
      __builtin_amdgcn_global_load_lds(                                          \
          (const __attribute__((address_space(1))) void*)(A + (size_t)(m0 + row_) * H + (K0) + lc),  \
          (__attribute__((address_space(3))) void*)(&As[BUF][row_ * 64 + lc]), 16, 0, 0);            \
      __builtin_amdgcn_global_load_lds(                                          \
          (const __attribute__((address_space(1))) void*)(Bw + (size_t)(n0 + row_) * H + (K0) + lc), \
          (__attribute__((address_space(3))) void*)(&Bs[BUF][row_ * 64 + lc]), 16, 0, 0);            \
    }                                                                            \
  } while (0)

__global__ __launch_bounds__(256, 1) void gemm_bt_bias(
    const u16* __restrict__ A, const u16* __restrict__ Bw,
    const float* __restrict__ bias, float* __restrict__ C, int N)
{
  __shared__ u16 As[2][128 * 64];
  __shared__ u16 Bs[2][128 * 64];
  const int tid = threadIdx.x;
  const int lane = tid & 63;
  const int wid = tid >> 6;
  const unsigned id = blockIdx.x + gridDim.x * blockIdx.y;  // 0..7999
  const unsigned xcd = id & 7u, seq = id >> 3;              // seq 0..999
  const int m0 = (int)(xcd * 4 + (seq & 3u)) * 128;         // m-tile 0..31
  const int n0 = (int)(seq >> 2) * 128;                     // n-tile 0..249
  const int wr = wid >> 1, wc = wid & 1;
  const int lr = lane >> 3;
  const int lc = (lane & 7) * 8;
  f32x4 acc[4][4] = {};

  STAGE_GEMM(0, 0);
  asm volatile("s_waitcnt vmcnt(0)" ::: "memory");
  __syncthreads();

  int cur = 0;
  for (int kt = 0; kt < 16; ++kt) {
    if (kt < 15) {
      if (cur == 0) STAGE_GEMM(1, (kt + 1) * 64);
      else          STAGE_GEMM(0, (kt + 1) * 64);
    }
    #pragma unroll
    for (int ks = 0; ks < 2; ++ks) {
      short8 af[4], bfr[4];
      #pragma unroll
      for (int i = 0; i < 4; ++i) {
        af[i]  = *(const short8*)&As[cur][(wr * 64 + i * 16 + (lane & 15)) * 64 + ks * 32 + (lane >> 4) * 8];
        bfr[i] = *(const short8*)&Bs[cur][(wc * 64 + i * 16 + (lane & 15)) * 64 + ks * 32 + (lane >> 4) * 8];
      }
      #pragma unroll
      for (int i = 0; i < 4; ++i) {
        #pragma unroll
        for (int jj = 0; jj < 4; ++jj)
          acc[i][jj] = mfma16(af[i], bfr[jj], acc[i][jj]);
      }
    }
    asm volatile("s_waitcnt vmcnt(0)" ::: "memory");
    __syncthreads();
    cur ^= 1;
  }

  #pragma unroll
  for (int jj = 0; jj < 4; ++jj) {
    const int col = n0 + wc * 64 + jj * 16 + (lane & 15);
    const float bv = bias[col];
    #pragma unroll
    for (int i = 0; i < 4; ++i) {
      const int rbase = m0 + wr * 64 + i * 16 + (lane >> 4) * 4;
      #pragma unroll
      for (int r = 0; r < 4; ++r)
        C[(size_t)(rbase + r) * N + col] = acc[i][jj][r] + bv;
    }
  }
}

// ---------------- launch ----------------

extern "C" void kernel_launch(void* const* d_in, const int* in_sizes, int n_in,
                              void* d_out, int out_size, void* d_ws, size_t ws_size,
                              hipStream_t stream) {
  const int*   x    = (const int*)d_in[0];
  const float* h0   = (const float*)d_in[1];
  const float* c0   = (const float*)d_in[2];
  const float* emb  = (const float*)d_in[3];
  const float* W_ih = (const float*)d_in[4];
  const float* W_hh = (const float*)d_in[5];
  const float* b_ih = (const float*)d_in[6];
  const float* b_hh = (const float*)d_in[7];
  const float* fc_W = (const float*)d_in[8];
  const float* fc_b = (const float*)d_in[9];
  float* out = (float*)d_out;
  char* ws = (char*)d_ws;

  size_t off = 0;
  u16* WihB = (u16*)(ws + off); off += (size_t)NL * G4 * H * 2;   // 33.6 MB
  u16* WhhB = (u16*)(ws + off); off += (size_t)NL * G4 * H * 2;   // 33.6 MB
  u16* fcWB = (u16*)(ws + off); off += (size_t)VOCAB * H * 2;     // 65.5 MB
  u16* h0B  = (u16*)(ws + off); off += (size_t)NL * NB * H * 2;
  float* biasB = (float*)(ws + off); off += (size_t)NL * G4 * 4;
  u16* ybufs = (u16*)(ws + off); off += (size_t)(NL + 1) * YSZ * 2;  // 41.9 MB
  if (ws_size < off) return;  // fail loudly rather than corrupt

  int n8;
  n8 = NL * G4 * H / 8;  cvt_bf16<<<(n8 + 255) / 256, 256, 0, stream>>>(W_ih, WihB, n8);
  n8 = NL * G4 * H / 8;  cvt_bf16<<<(n8 + 255) / 256, 256, 0, stream>>>(W_hh, WhhB, n8);
  n8 = VOCAB * H / 8;    cvt_bf16<<<(n8 + 255) / 256, 256, 0, stream>>>(fc_W, fcWB, n8);
  n8 = NL * NB * H / 8;  cvt_bf16<<<(n8 + 255) / 256, 256, 0, stream>>>(h0, h0B, n8);
  bias_sum<<<(NL * G4 + 255) / 256, 256, 0, stream>>>(b_ih, b_hh, biasB, NL * G4);
  // sentinel refill of the 4 polled Y buffers (every launch; replay safety)
  fill_sent<<<8192, 256, 0, stream>>>((u32x4v*)(ybufs + YSZ));
  gather_emb<<<SEQ * NB, 256, 0, stream>>>(x, emb, ybufs);

  float* hfin = out + (size_t)SEQ * NB * VOCAB;
  float* cfin = hfin + (size_t)NL * NB * H;

  lstm_scan<<<NL * 64, 256, 147456, stream>>>(
      ybufs, ybufs, WihB, WhhB, biasB, h0B, c0, hfin, cfin);

  gemm_bt_bias<<<dim3(32, 250), 256, 0, stream>>>(
      ybufs + (size_t)NL * YSZ, fcWB, fc_b, out, VOCAB);
}

// Round 15
// 1583.229 us; speedup vs baseline: 1.1261x; 1.1261x over previous
//
#include <hip/hip_runtime.h>
#include <hip/hip_bf16.h>

typedef unsigned short u16;
typedef short short8 __attribute__((ext_vector_type(8)));
typedef u16 u16x8 __attribute__((ext_vector_type(8)));
typedef float f32x4 __attribute__((ext_vector_type(4)));
typedef unsigned u32x4v __attribute__((ext_vector_type(4)));

#define H 1024
#define NB 16
#define SEQ 256
#define NL 4
#define VOCAB 32000
#define G4 4096
#define YSZ ((size_t)SEQ * NB * H)
#define SENT 0xFFFFFFFFu

__device__ __forceinline__ u16 f2bf(float f) {
  __hip_bfloat16 h = __float2bfloat16(f);
  return *reinterpret_cast<u16*>(&h);
}
__device__ __forceinline__ float sigm(float x) { return 1.0f / (1.0f + __expf(-x)); }
__device__ __forceinline__ float tanhfast(float x) { return 2.0f / (1.0f + __expf(-2.0f * x)) - 1.0f; }

__device__ __forceinline__ f32x4 mfma16(short8 a, short8 b, f32x4 c) {
  return __builtin_amdgcn_mfma_f32_16x16x32_bf16(a, b, c, 0, 0, 0);
}

// Device-coherent 16B load: bypass L1/L2, served by the MALL.
template <int BOFF>
__device__ __forceinline__ short8 ldg_sc(const u16* p) {
  short8 r;
  asm volatile("global_load_dwordx4 %0, %1, off offset:%2 sc0 sc1"
               : "=&v"(r) : "v"(p), "n"(BOFF));
  return r;
}
// Cached 16B load via asm (keeps vmcnt accounting deterministic).
template <int BOFF>
__device__ __forceinline__ short8 ldg_ca(const u16* p) {
  short8 r;
  asm volatile("global_load_dwordx4 %0, %1, off offset:%2"
               : "=&v"(r) : "v"(p), "n"(BOFF));
  return r;
}

#define LD8SC(d, p)                                            \
  do {                                                         \
    d[0] = ldg_sc<0 * 64>(p); d[1] = ldg_sc<1 * 64>(p);        \
    d[2] = ldg_sc<2 * 64>(p); d[3] = ldg_sc<3 * 64>(p);        \
    d[4] = ldg_sc<4 * 64>(p); d[5] = ldg_sc<5 * 64>(p);        \
    d[6] = ldg_sc<6 * 64>(p); d[7] = ldg_sc<7 * 64>(p);        \
  } while (0)
#define LD8CA(d, p)                                            \
  do {                                                         \
    d[0] = ldg_ca<0 * 64>(p); d[1] = ldg_ca<1 * 64>(p);        \
    d[2] = ldg_ca<2 * 64>(p); d[3] = ldg_ca<3 * 64>(p);        \
    d[4] = ldg_ca<4 * 64>(p); d[5] = ldg_ca<5 * 64>(p);        \
    d[6] = ldg_ca<6 * 64>(p); d[7] = ldg_ca<7 * 64>(p);        \
  } while (0)

// max over all 32 dwords of an 8-packet set; == SENT iff ANY dword unwritten.
// (Round-14 lesson: per-packet selective reload costs serial VALU on the beat
// critical path and regressed 18%; full pipelined reload is cheaper.)
__device__ __forceinline__ unsigned maxpk(const short8 (&f)[8]) {
  unsigned mx = 0u;
  #pragma unroll
  for (int i = 0; i < 8; ++i) {
    u32x4v d = __builtin_bit_cast(u32x4v, f[i]);
    mx = d[0] > mx ? d[0] : mx;
    mx = d[1] > mx ? d[1] : mx;
    mx = d[2] > mx ? d[2] : mx;
    mx = d[3] > mx ? d[3] : mx;
  }
  return mx;
}

// ---------------- small prep kernels ----------------

__global__ void cvt_bf16(const float* __restrict__ in, u16* __restrict__ out, int n8) {
  const int i = blockIdx.x * blockDim.x + threadIdx.x;
  if (i >= n8) return;
  const float4 a = ((const float4*)in)[2 * i];
  const float4 b = ((const float4*)in)[2 * i + 1];
  u16x8 o;
  o[0] = f2bf(a.x); o[1] = f2bf(a.y); o[2] = f2bf(a.z); o[3] = f2bf(a.w);
  o[4] = f2bf(b.x); o[5] = f2bf(b.y); o[6] = f2bf(b.z); o[7] = f2bf(b.w);
  *(u16x8*)(out + (size_t)i * 8) = o;
}

__global__ void bias_sum(const float* __restrict__ a, const float* __restrict__ b,
                         float* __restrict__ o, int n) {
  const int i = blockIdx.x * blockDim.x + threadIdx.x;
  if (i < n) o[i] = a[i] + b[i];
}

// sentinel refill of the polled Y buffers (every launch: replay safety).
__global__ void fill_sent(u32x4v* __restrict__ p) {
  const int i = blockIdx.x * blockDim.x + threadIdx.x;
  u32x4v v = {SENT, SENT, SENT, SENT};
  p[i] = v;
}

__global__ void gather_emb(const int* __restrict__ x, const float* __restrict__ emb,
                           u16* __restrict__ Y) {
  const int row = blockIdx.x;
  const int tok = x[row];
  const float4 v = ((const float4*)(emb + (size_t)tok * H))[threadIdx.x];
  ushort4 o;
  o.x = f2bf(v.x); o.y = f2bf(v.y); o.z = f2bf(v.z); o.w = f2bf(v.w);
  *(ushort4*)(Y + (size_t)row * H + threadIdx.x * 4) = o;
}

// ---------------- LSTM: 4-layer wavefront, K-split waves, sentinel-stamped ----------------
// ROUND-13 PROVEN FORM (1108 us): full-reload sentinel poll; smh LDS hop +
// wave0 32x16B dwordx4 publish (16B stores avoid the 4x HBM write
// amplification that round-14's 8B dwordx2 publish caused).

__global__ __launch_bounds__(256, 1) void lstm_scan(
    const u16* __restrict__ ybase_r, u16* __restrict__ ybase_w,
    const u16* __restrict__ Wih_all, const u16* __restrict__ Whh_all,
    const float* __restrict__ bias_all, const u16* __restrict__ h0_all,
    const float* __restrict__ c0_all, float* __restrict__ hfin_all,
    float* __restrict__ cfin_all)
{
  extern __shared__ u16 sm[];  // [0,65536): Whh frags; [65536,73728): reduce; [73728,73984): smh
  u16* __restrict__ smw = sm;
  f32x4* __restrict__ lred = (f32x4*)(sm + 65536);
  u16* __restrict__ smh = sm + 73728;

  const int tid = threadIdx.x;
  const int lane = tid & 63;
  const int wid = tid >> 6;
  const int l = blockIdx.x >> 6;
  const int jgrp = blockIdx.x & 63;
  const int jbase = jgrp * 16;
  const int b = lane & 15;
  const int lg = lane >> 4;
  const int m = lane & 15;
  const int j = jbase + wid * 4 + lg;

  const u16* __restrict__ Yin  = ybase_r + (size_t)l * YSZ;
  u16* __restrict__ Yout       = ybase_w + (size_t)(l + 1) * YSZ;
  const u16* __restrict__ Wih  = Wih_all + (size_t)l * G4 * H;
  const u16* __restrict__ Whh  = Whh_all + (size_t)l * G4 * H;
  const float* __restrict__ bias = bias_all + (size_t)l * G4;
  const u16* __restrict__ h0b  = h0_all + (size_t)l * NB * H;
  const float* __restrict__ c0 = c0_all + (size_t)l * NB * H;
  float* __restrict__ hfin     = hfin_all + (size_t)l * NB * H;
  float* __restrict__ cfin     = cfin_all + (size_t)l * NB * H;

  // ---- stage Whh slice into LDS, fragment-ordered (conflict-free) ----
  // (rt, ks, lane) at u16 offset rt*16384 + ks*512 + lane*8, ks = wid*8+i.
  #pragma unroll
  for (int rt = 0; rt < 4; ++rt) {
    const size_t ar = (size_t)((m & 3) * H + jbase + rt * 4 + (m >> 2));
    const u16* src = Whh + ar * H + lg * 8;
    #pragma unroll
    for (int i = 0; i < 8; ++i) {
      const int ks = wid * 8 + i;
      short8 w = *(const short8*)(src + ks * 32);
      *(short8*)(smw + (size_t)rt * 16384 + (size_t)ks * 512 + lane * 8) = w;
    }
  }
  // ---- Wih k-quarter -> registers (asm-pinned; round-11 proved streaming
  // it from cache costs 1.4 GB FETCH and 2.1x once waits are honest) ----
  short8 WI[32];
  #pragma unroll
  for (int rt = 0; rt < 4; ++rt) {
    const size_t ar = (size_t)((m & 3) * H + jbase + rt * 4 + (m >> 2));
    const u16* src = Wih + ar * H + lg * 8;
    #pragma unroll
    for (int i = 0; i < 8; ++i) {
      WI[rt * 8 + i] = *(const short8*)(src + (wid * 8 + i) * 32);
      asm volatile("" : "+v"(WI[rt * 8 + i]));
    }
  }
  __syncthreads();

  f32x4 bias4;
  bias4[0] = bias[0 * H + j];
  bias4[1] = bias[1 * H + j];
  bias4[2] = bias[2 * H + j];
  bias4[3] = bias[3 * H + j];

  float c = c0[b * H + j];
  const int boff = b * H + lg * 8;           // per-lane column base within a [16,1024] tile
  const int kboff = wid * 256;               // wave's k-quarter offset (8 ks * 32 u16)
  const u16* __restrict__ smwv = smw + (size_t)wid * 4096 + lane * 8;  // + rt*16384 + i*512

  for (int t = 0; t < SEQ; ++t) {
    const u16* xw = Yin + (size_t)t * (NB * H) + boff + kboff;
    const u16* hw = (t == 0 ? h0b : Yout + (size_t)(t - 1) * (NB * H)) + boff + kboff;

    short8 fx[8], fh[8];
    const bool needx = (l > 0);
    const bool needh = (t > 0);
    if (!needx) LD8CA(fx, xw);   // gather_emb output: ready before launch
    if (!needh) LD8CA(fh, hw);   // h0: dispatch input

    if (needx || needh) {
      // sentinel poll: reload waited sets until no dword is 0xFFFFFFFF
      unsigned ok;
      do {
        if (needx) LD8SC(fx, xw);
        if (needh) LD8SC(fh, hw);
        asm volatile("s_waitcnt vmcnt(0)" ::: "memory");
        unsigned mx = 0u;
        if (needx) { unsigned a = maxpk(fx); mx = a > mx ? a : mx; }
        if (needh) { unsigned a = maxpk(fh); mx = a > mx ? a : mx; }
        ok = (mx != SENT);
      } while (!__all(ok));
      __builtin_amdgcn_sched_barrier(0);
    } else {
      asm volatile("s_waitcnt vmcnt(0)" ::: "memory");
      __builtin_amdgcn_sched_barrier(0);
    }

    f32x4 a0 = {0.f, 0.f, 0.f, 0.f};
    f32x4 a1 = {0.f, 0.f, 0.f, 0.f};
    f32x4 a2 = {0.f, 0.f, 0.f, 0.f};
    f32x4 a3 = {0.f, 0.f, 0.f, 0.f};

    // Zx = Wih @ x_t (register A-frags)
    #pragma unroll
    for (int i = 0; i < 8; ++i) {
      a0 = mfma16(WI[0 * 8 + i], fx[i], a0);
      a1 = mfma16(WI[1 * 8 + i], fx[i], a1);
      a2 = mfma16(WI[2 * 8 + i], fx[i], a2);
      a3 = mfma16(WI[3 * 8 + i], fx[i], a3);
    }
    // += Whh @ h_{t-1} (A-frags from LDS)
    #pragma unroll
    for (int i = 0; i < 8; ++i) {
      short8 w0 = *(const short8*)(smwv + 0 * 16384 + i * 512);
      short8 w1 = *(const short8*)(smwv + 1 * 16384 + i * 512);
      short8 w2 = *(const short8*)(smwv + 2 * 16384 + i * 512);
      short8 w3 = *(const short8*)(smwv + 3 * 16384 + i * 512);
      a0 = mfma16(w0, fh[i], a0);
      a1 = mfma16(w1, fh[i], a1);
      a2 = mfma16(w2, fh[i], a2);
      a3 = mfma16(w3, fh[i], a3);
    }

    // ---- cross-wave reduce: wave w keeps row-tile w, ships the rest via LDS ----
    if (wid != 0) lred[(0 * 4 + wid) * 64 + lane] = a0;
    if (wid != 1) lred[(1 * 4 + wid) * 64 + lane] = a1;
    if (wid != 2) lred[(2 * 4 + wid) * 64 + lane] = a2;
    if (wid != 3) lred[(3 * 4 + wid) * 64 + lane] = a3;
    __syncthreads();

    f32x4 z4 = bias4;
    if (wid == 0)      z4 += a0;
    else if (wid == 1) z4 += a1;
    else if (wid == 2) z4 += a2;
    else               z4 += a3;
    #pragma unroll
    for (int w2 = 0; w2 < 4; ++w2)
      if (w2 != wid) z4 += lred[(wid * 4 + w2) * 64 + lane];

    const float ig = sigm(z4[0]);
    const float fg = sigm(z4[1]);
    const float gg = tanhfast(z4[2]);
    const float og = sigm(z4[3]);
    c = fg * c + ig * gg;
    const float h = og * tanhfast(c);

    smh[b * 16 + wid * 4 + lg] = f2bf(h);
    if (t == SEQ - 1) {
      hfin[b * H + j] = h;
      cfin[b * H + j] = c;
    }

    __syncthreads();  // smh complete
    // publish: fire-and-forget 16B sc stores (no drain, no flag — data IS the flag)
    if (wid == 0 && lane < 32) {
      const int br = lane >> 1, half = lane & 1;
      u16x8 pv = *(const u16x8*)&smh[br * 16 + half * 8];
      const u16* dst = Yout + (size_t)t * (NB * H) + (size_t)br * H + jbase + half * 8;
      asm volatile("global_store_dwordx4 %0, %1, off sc0 sc1"
                   :: "v"(dst), "v"(pv) : "memory");
    }
  }
}

// ---------------- bf16 GEMM: 128x128, XCD m-clustered, 2-phase dbuf staging ----------------
// (Round-14 proven: -80 us vs single-buffer.) Stage next K-tile BEFORE the
// MFMA block; one vmcnt(0) + barrier per tile.

#define STAGE_GEMM(BUF, K0)                                                      \
  do {                                                                           \
    _Pragma("unroll")                                                            \
    for (int cc = 0; cc < 4; ++cc) {                                             \
      const int row_ = wid * 32 + cc * 8 + lr;                                   \
      __builtin_amdgcn_global_load_lds(                                          \
          (const __attribute__((address_space(1))) void*)(A + (size_t)(m0 + row_) * H + (K0) + lc),  \
          (__attribute__((address_space(3))) void*)(&As[BUF][row_ * 64 + lc]), 16, 0, 0);            \
      __builtin_amdgcn_global_load_lds(                                          \
          (const __attribute__((address_space(1))) void*)(Bw + (size_t)(n0 + row_) * H + (K0) + lc), \
          (__attribute__((address_space(3))) void*)(&Bs[BUF][row_ * 64 + lc]), 16, 0, 0);            \
    }                                                                            \
  } while (0)

__global__ __launch_bounds__(256, 1) void gemm_bt_bias(
    const u16* __restrict__ A, const u16* __restrict__ Bw,
    const float* __restrict__ bias, float* __restrict__ C, int N)
{
  __shared__ u16 As[2][128 * 64];
  __shared__ u16 Bs[2][128 * 64];
  const int tid = threadIdx.x;
  const int lane = tid & 63;
  const int wid = tid >> 6;
  const unsigned id = blockIdx.x + gridDim.x * blockIdx.y;  // 0..7999
  const unsigned xcd = id & 7u, seq = id >> 3;              // seq 0..999
  const int m0 = (int)(xcd * 4 + (seq & 3u)) * 128;         // m-tile 0..31
  const int n0 = (int)(seq >> 2) * 128;                     // n-tile 0..249
  const int wr = wid >> 1, wc = wid & 1;
  const int lr = lane >> 3;
  const int lc = (lane & 7) * 8;
  f32x4 acc[4][4] = {};

  STAGE_GEMM(0, 0);
  asm volatile("s_waitcnt vmcnt(0)" ::: "memory");
  __syncthreads();

  int cur = 0;
  for (int kt = 0; kt < 16; ++kt) {
    if (kt < 15) {
      if (cur == 0) STAGE_GEMM(1, (kt + 1) * 64);
      else          STAGE_GEMM(0, (kt + 1) * 64);
    }
    #pragma unroll
    for (int ks = 0; ks < 2; ++ks) {
      short8 af[4], bfr[4];
      #pragma unroll
      for (int i = 0; i < 4; ++i) {
        af[i]  = *(const short8*)&As[cur][(wr * 64 + i * 16 + (lane & 15)) * 64 + ks * 32 + (lane >> 4) * 8];
        bfr[i] = *(const short8*)&Bs[cur][(wc * 64 + i * 16 + (lane & 15)) * 64 + ks * 32 + (lane >> 4) * 8];
      }
      #pragma unroll
      for (int i = 0; i < 4; ++i) {
        #pragma unroll
        for (int jj = 0; jj < 4; ++jj)
          acc[i][jj] = mfma16(af[i], bfr[jj], acc[i][jj]);
      }
    }
    asm volatile("s_waitcnt vmcnt(0)" ::: "memory");
    __syncthreads();
    cur ^= 1;
  }

  #pragma unroll
  for (int jj = 0; jj < 4; ++jj) {
    const int col = n0 + wc * 64 + jj * 16 + (lane & 15);
    const float bv = bias[col];
    #pragma unroll
    for (int i = 0; i < 4; ++i) {
      const int rbase = m0 + wr * 64 + i * 16 + (lane >> 4) * 4;
      #pragma unroll
      for (int r = 0; r < 4; ++r)
        C[(size_t)(rbase + r) * N + col] = acc[i][jj][r] + bv;
    }
  }
}

// ---------------- launch ----------------

extern "C" void kernel_launch(void* const* d_in, const int* in_sizes, int n_in,
                              void* d_out, int out_size, void* d_ws, size_t ws_size,
                              hipStream_t stream) {
  const int*   x    = (const int*)d_in[0];
  const float* h0   = (const float*)d_in[1];
  const float* c0   = (const float*)d_in[2];
  const float* emb  = (const float*)d_in[3];
  const float* W_ih = (const float*)d_in[4];
  const float* W_hh = (const float*)d_in[5];
  const float* b_ih = (const float*)d_in[6];
  const float* b_hh = (const float*)d_in[7];
  const float* fc_W = (const float*)d_in[8];
  const float* fc_b = (const float*)d_in[9];
  float* out = (float*)d_out;
  char* ws = (char*)d_ws;

  size_t off = 0;
  u16* WihB = (u16*)(ws + off); off += (size_t)NL * G4 * H * 2;   // 33.6 MB
  u16* WhhB = (u16*)(ws + off); off += (size_t)NL * G4 * H * 2;   // 33.6 MB
  u16* fcWB = (u16*)(ws + off); off += (size_t)VOCAB * H * 2;     // 65.5 MB
  u16* h0B  = (u16*)(ws + off); off += (size_t)NL * NB * H * 2;
  float* biasB = (float*)(ws + off); off += (size_t)NL * G4 * 4;
  u16* ybufs = (u16*)(ws + off); off += (size_t)(NL + 1) * YSZ * 2;  // 41.9 MB
  if (ws_size < off) return;  // fail loudly rather than corrupt

  int n8;
  n8 = NL * G4 * H / 8;  cvt_bf16<<<(n8 + 255) / 256, 256, 0, stream>>>(W_ih, WihB, n8);
  n8 = NL * G4 * H / 8;  cvt_bf16<<<(n8 + 255) / 256, 256, 0, stream>>>(W_hh, WhhB, n8);
  n8 = VOCAB * H / 8;    cvt_bf16<<<(n8 + 255) / 256, 256, 0, stream>>>(fc_W, fcWB, n8);
  n8 = NL * NB * H / 8;  cvt_bf16<<<(n8 + 255) / 256, 256, 0, stream>>>(h0, h0B, n8);
  bias_sum<<<(NL * G4 + 255) / 256, 256, 0, stream>>>(b_ih, b_hh, biasB, NL * G4);
  // sentinel refill of the 4 polled Y buffers (every launch; replay safety)
  fill_sent<<<8192, 256, 0, stream>>>((u32x4v*)(ybufs + YSZ));
  gather_emb<<<SEQ * NB, 256, 0, stream>>>(x, emb, ybufs);

  float* hfin = out + (size_t)SEQ * NB * VOCAB;
  float* cfin = hfin + (size_t)NL * NB * H;

  lstm_scan<<<NL * 64, 256, 147968, stream>>>(
      ybufs, ybufs, WihB, WhhB, biasB, h0B, c0, hfin, cfin);

  gemm_bt_bias<<<dim3(32, 250), 256, 0, stream>>>(
      ybufs + (size_t)NL * YSZ, fcWB, fc_b, out, VOCAB);
}